// Round 4
// baseline (442.665 us; speedup 1.0000x reference)
//
#include <hip/hip_runtime.h>

#define HID 32
#define SEQ 512
#define GROUPS_PER_BLOCK 8
#define BLOCK (GROUPS_PER_BLOCK * 32)

typedef float v2f __attribute__((ext_vector_type(2)));

__device__ __forceinline__ float fast_exp(float x) {
    // e^x = 2^(x * log2(e)), v_exp_f32 ~1 ulp
    return __builtin_amdgcn_exp2f(x * 1.44269504088896340736f);
}
__device__ __forceinline__ float fast_rcp(float x) {
    return __builtin_amdgcn_rcpf(x);
}
__device__ __forceinline__ float sigmoid_f(float x) {
    return fast_rcp(1.0f + fast_exp(-x));
}
__device__ __forceinline__ float tanh_f(float x) {
    // tanh(x) = 1 - 2/(1 + e^{2x}); saturates correctly at +/-inf
    return 1.0f - 2.0f * fast_rcp(1.0f + fast_exp(2.0f * x));
}

// Broadcast lane J (0..31) within each 32-lane half of the wave.
// ds_swizzle BitMode: new_lane = ((lane & and) | or) ^ xor; offset = (xor<<10)|(or<<5)|and.
#define BCAST32(v, J) \
    __int_as_float(__builtin_amdgcn_ds_swizzle(__float_as_int(v), ((J) << 5)))

// Occupancy is LAUNCH-limited at 2 waves/SIMD (512 blocks -> 2 blocks/CU),
// so the RA has no occupancy reason to keep arch-VGPR count low.
__global__ __launch_bounds__(BLOCK)
__attribute__((amdgpu_waves_per_eu(1, 2)))
void lstm_fused_kernel(
    const float* __restrict__ x,       // [B, T, 1]
    const float* __restrict__ W_ih,    // [4H, 1]
    const float* __restrict__ W_hh,    // [4H, H] row-major
    const float* __restrict__ b_ih,    // [4H]
    const float* __restrict__ b_hh,    // [4H]
    const float* __restrict__ W_head,  // [1, H]
    const float* __restrict__ b_head,  // [1]
    float* __restrict__ out)           // [B, 1]
{
    // Stage W_hh transposed into LDS: Wl[j][g] with padded stride 129 (conflict-free)
    __shared__ float Wl[32 * 129];
    const int tid = threadIdx.x;
    for (int idx = tid; idx < 128 * 32; idx += BLOCK) {
        const int g = idx >> 5;   // gate-row 0..127
        const int j = idx & 31;   // hidden col 0..31
        Wl[j * 129 + g] = W_hh[idx];
    }
    __syncthreads();

    const int k   = tid & 31;   // hidden unit owned by this lane
    const int grp = tid >> 5;   // batch group within block (0..7)
    const int b   = blockIdx.x * GROUPS_PER_BLOCK + grp;

    // Weights as packed gate-pairs: w_if[j] = (Wi[k][j], Wf[k][j]), w_go[j] = (Wg, Wo).
    v2f w_if[HID], w_go[HID];
#pragma unroll
    for (int j = 0; j < HID; ++j) {
        w_if[j] = (v2f){ Wl[j * 129 +       k], Wl[j * 129 + 32 + k] };
        w_go[j] = (v2f){ Wl[j * 129 + 64 + k], Wl[j * 129 + 96 + k] };
    }

    const v2f bv_if = { b_ih[k]      + b_hh[k],      b_ih[32 + k] + b_hh[32 + k] };
    const v2f bv_go = { b_ih[64 + k] + b_hh[64 + k], b_ih[96 + k] + b_hh[96 + k] };
    const v2f uv_if = { W_ih[k],      W_ih[32 + k] };
    const v2f uv_go = { W_ih[64 + k], W_ih[96 + k] };

    const float* xb = x + (size_t)b * SEQ;  // I == 1, so x[b][t][0] = xb[t]

    float h = 0.0f, c = 0.0f;

    // JS2(M): gate FMAs for j = 2M and 2M+1, fully pinned as inline asm.
    //  - hv = (h[2M], h[2M+1]) built from two immediate ds_swizzle broadcasts;
    //    the two swizzle dests coalesce into the aligned VGPR pair (no movs).
    //  - v_pk_fma_f32 with op_sel splats one half of hv across both gate
    //    lanes: op_sel_hi:[1,0,1] -> multiply by hv.lo (= h[2M]);
    //    op_sel:[0,1,0] op_sel_hi:[1,1,1] -> multiply by hv.hi (= h[2M+1]).
    //  - per-gate fma order is j ascending, identical to the scalar version
    //    (bitwise-identical numerics).
    //  - weights are direct "v" operands: 32 VGPR-use sites per timestep make
    //    AGPR parking cost 2 copies per site -> RA must keep them resident.
#define JS2(M) { \
        const v2f hv = { BCAST32(h, 2*(M)), BCAST32(h, 2*(M)+1) }; \
        asm("v_pk_fma_f32 %0, %2, %4, %0 op_sel_hi:[1,0,1]\n\t" \
            "v_pk_fma_f32 %1, %3, %4, %1 op_sel_hi:[1,0,1]\n\t" \
            "v_pk_fma_f32 %0, %5, %4, %0 op_sel:[0,1,0] op_sel_hi:[1,1,1]\n\t" \
            "v_pk_fma_f32 %1, %6, %4, %1 op_sel:[0,1,0] op_sel_hi:[1,1,1]" \
            : "+v"(aif), "+v"(ago) \
            : "v"(w_if[2*(M)]), "v"(w_go[2*(M)]), "v"(hv), \
              "v"(w_if[2*(M)+1]), "v"(w_go[2*(M)+1])); \
    }

    for (int t0 = 0; t0 < SEQ; t0 += 32) {
        // lane k prefetches x[b][t0+k]; broadcast per-step via shuffle
        const float xv = xb[t0 + k];
#pragma unroll 4
        for (int tt = 0; tt < 32; ++tt) {
            const float xt = __shfl(xv, tt, 32);
            const v2f xtv = { xt, xt };
            v2f aif = __builtin_elementwise_fma(xtv, uv_if, bv_if);
            v2f ago = __builtin_elementwise_fma(xtv, uv_go, bv_go);
            JS2(0)  JS2(1)  JS2(2)  JS2(3)
            JS2(4)  JS2(5)  JS2(6)  JS2(7)
            JS2(8)  JS2(9)  JS2(10) JS2(11)
            JS2(12) JS2(13) JS2(14) JS2(15)
            const float ig = sigmoid_f(aif.x);
            const float fg = sigmoid_f(aif.y);
            const float gg = tanh_f(ago.x);
            const float og = sigmoid_f(ago.y);
            c = __builtin_fmaf(fg, c, ig * gg);
            h = og * tanh_f(c);
        }
    }
#undef JS2

    // head: out[b] = sum_k h[k] * W_head[0][k] + b_head[0]
    float v = h * W_head[k];
#pragma unroll
    for (int off = 16; off >= 1; off >>= 1)
        v += __shfl_xor(v, off, 32);
    if (k == 0) out[b] = v + b_head[0];
}

extern "C" void kernel_launch(void* const* d_in, const int* in_sizes, int n_in,
                              void* d_out, int out_size, void* d_ws, size_t ws_size,
                              hipStream_t stream) {
    const float* x      = (const float*)d_in[0];
    const float* W_ih   = (const float*)d_in[1];
    const float* W_hh   = (const float*)d_in[2];
    const float* b_ih   = (const float*)d_in[3];
    const float* b_hh   = (const float*)d_in[4];
    const float* W_head = (const float*)d_in[5];
    const float* b_head = (const float*)d_in[6];
    float* out = (float*)d_out;

    const int B = in_sizes[0] / SEQ;          // 4096
    const int grid = B / GROUPS_PER_BLOCK;    // 512 blocks

    lstm_fused_kernel<<<grid, BLOCK, 0, stream>>>(
        x, W_ih, W_hh, b_ih, b_hh, W_head, b_head, out);
}